// Round 3
// baseline (156.817 us; speedup 1.0000x reference)
//
#include <hip/hip_runtime.h>
#include <math.h>

// LSH attention: B=2, H=8, S=2048, D=64, 6 bits -> 64 buckets, exact-match.
// Phase 1: bucket codes for Q and K (fused)
// Phase 2: stable counting sort of query and key indices by bucket
// Phase 2.5: work queue of (bucket, query-tile) items via block-wide prefix scan
// Phase 3: block per work item (8 queries); stage K^T / V chunk in LDS; online
//          softmax over 64-key chunks, lane=key for scores, lane=dim for PV.

constexpr int S_LEN = 2048;
constexpr int D = 64;
constexpr int NHASH = 6;
constexpr int BH = 16;     // B*H
constexpr int NB = 64;     // 2^NHASH
constexpr int QTILE = 8;   // queries per work item (4 waves x 2)
constexpr int MAX_WORK = 4096 + 1024;  // sum ceil(nq/8) <= S*BH/8 + #buckets

__device__ __forceinline__ float wave_sum(float v) {
#pragma unroll
    for (int off = 32; off >= 1; off >>= 1) v += __shfl_xor(v, off, 64);
    return v;
}
__device__ __forceinline__ float wave_max(float v) {
#pragma unroll
    for (int off = 32; off >= 1; off >>= 1) v = fmaxf(v, __shfl_xor(v, off, 64));
    return v;
}

// ---- Phase 1: bucket codes for Q and K in one dispatch. One wave per vector.
__global__ __launch_bounds__(256) void lsh_buckets2(const float* __restrict__ Q,
                                                    const float* __restrict__ K,
                                                    const float* __restrict__ rot,
                                                    int* __restrict__ qb,
                                                    int* __restrict__ kb) {
    const int gw   = (blockIdx.x * 256 + threadIdx.x) >> 6;
    const int lane = threadIdx.x & 63;
    const bool isK = gw >= BH * S_LEN;
    const int wid  = isK ? gw - BH * S_LEN : gw;
    const float* X = isK ? K : Q;
    int* dst       = isK ? kb : qb;
    const int h    = (wid >> 11) & 7;

    const float x  = X[(size_t)wid * D + lane];
    const float* r = rot + (size_t)h * NHASH * D + lane;
    float p0 = x * r[0 * D], p1 = x * r[1 * D], p2 = x * r[2 * D];
    float p3 = x * r[3 * D], p4 = x * r[4 * D], p5 = x * r[5 * D];
#pragma unroll
    for (int off = 32; off >= 1; off >>= 1) {
        p0 += __shfl_xor(p0, off, 64);
        p1 += __shfl_xor(p1, off, 64);
        p2 += __shfl_xor(p2, off, 64);
        p3 += __shfl_xor(p3, off, 64);
        p4 += __shfl_xor(p4, off, 64);
        p5 += __shfl_xor(p5, off, 64);
    }
    int bucket = (p0 > 0.f ? 1 : 0) | (p1 > 0.f ? 2 : 0) | (p2 > 0.f ? 4 : 0) |
                 (p3 > 0.f ? 8 : 0) | (p4 > 0.f ? 16 : 0) | (p5 > 0.f ? 32 : 0);
    if (lane == 0) dst[wid] = bucket;
}

// ---- Phase 2: stable counting sort, one block per (which, bh). which: 0=Q 1=K
__global__ __launch_bounds__(256) void lsh_build_lists2(const int* __restrict__ qbuckets,
                                                        const int* __restrict__ kbuckets,
                                                        int* __restrict__ q_start,
                                                        int* __restrict__ q_list,
                                                        int* __restrict__ k_start,
                                                        int* __restrict__ k_list) {
    __shared__ unsigned short hist[256][NB + 1];
    __shared__ int base[NB + 1];
    const int which = blockIdx.x >> 4;
    const int bh    = blockIdx.x & 15;
    const int tid   = threadIdx.x;
    const int* src  = (which ? kbuckets : qbuckets) + bh * S_LEN;
    int* bstart     = (which ? k_start : q_start) + bh * (NB + 1);
    int* blist      = (which ? k_list : q_list) + bh * S_LEN;

    for (int b = 0; b <= NB; ++b) hist[tid][b] = 0;

    int myb[8];
#pragma unroll
    for (int i = 0; i < 8; ++i) {
        int b = src[tid * 8 + i];
        myb[i] = b;
        hist[tid][b]++;
    }
    __syncthreads();

    if (tid < NB) {
        int run = 0;
        for (int c = 0; c < 256; ++c) {
            int t = hist[c][tid];
            hist[c][tid] = (unsigned short)run;
            run += t;
        }
        base[tid] = run;
    }
    __syncthreads();

    if (tid == 0) {
        int run = 0;
        for (int b = 0; b < NB; ++b) {
            int t = base[b];
            base[b] = run;
            bstart[b] = run;
            run += t;
        }
        base[NB] = run;
        bstart[NB] = run;
    }
    __syncthreads();

#pragma unroll
    for (int i = 0; i < 8; ++i) {
        int b   = myb[i];
        int ofs = base[b] + hist[tid][b];
        hist[tid][b]++;
        blist[ofs] = tid * 8 + i;
    }
}

// ---- Phase 2.5: work queue. 1 block, 1024 threads (thread == (bh,bucket)).
__global__ __launch_bounds__(1024) void build_workqueue(const int* __restrict__ q_start,
                                                        unsigned int* __restrict__ work,
                                                        int* __restrict__ wq_count) {
    const int tid  = threadIdx.x;          // == bh*64 + bucket
    const int lane = tid & 63;
    const int wave = tid >> 6;
    const int qs = q_start[tid + (tid >> 6)];       // bh*(NB+1)+bucket = tid + bh
    const int qe = q_start[tid + (tid >> 6) + 1];
    const int npass = (qe - qs + QTILE - 1) / QTILE;

    // inclusive scan within wave
    int x = npass;
#pragma unroll
    for (int off = 1; off < 64; off <<= 1) {
        int y = __shfl_up(x, off, 64);
        if (lane >= off) x += y;
    }
    __shared__ int wtot[16], woff[16];
    if (lane == 63) wtot[wave] = x;
    __syncthreads();
    if (tid < 16) {
        int t = wtot[tid];
#pragma unroll
        for (int off = 1; off < 16; off <<= 1) {
            int y = __shfl_up(t, off, 64);
            if (tid >= off) t += y;
        }
        woff[tid] = t - wtot[tid];
        if (tid == 15) *wq_count = t;
    }
    __syncthreads();
    int base = woff[wave] + x - npass;     // exclusive prefix for this thread
    for (int p = 0; p < npass; ++p) work[base + p] = ((unsigned)tid << 16) | p;
}

// ---- Phase 3: block per work item. 4 waves, 2 queries per wave.
__global__ __launch_bounds__(256) void lsh_attn_wq(const float* __restrict__ Q,
                                                   const float* __restrict__ K,
                                                   const float* __restrict__ V,
                                                   const int* __restrict__ q_start,
                                                   const int* __restrict__ q_list,
                                                   const int* __restrict__ k_start,
                                                   const int* __restrict__ k_list,
                                                   const unsigned int* __restrict__ work,
                                                   const int* __restrict__ wq_count,
                                                   float* __restrict__ out) {
    if ((int)blockIdx.x >= *wq_count) return;
    const unsigned e = work[blockIdx.x];
    const int bhb    = e >> 16;
    const int pass   = e & 0xFFFF;
    const int bh     = bhb >> 6;
    const int bucket = bhb & 63;
    const int tid    = threadIdx.x;
    const int wave   = tid >> 6;
    const int lane   = tid & 63;

    const int qs = q_start[bh * (NB + 1) + bucket];
    const int qe = q_start[bh * (NB + 1) + bucket + 1];
    const int ks = k_start[bh * (NB + 1) + bucket];
    const int ke = k_start[bh * (NB + 1) + bucket + 1];
    const int nq = qe - qs, nk = ke - ks;

    const int* ql    = q_list + bh * S_LEN + qs;
    const int* kl    = k_list + bh * S_LEN + ks;
    const float* Qb  = Q + (size_t)bh * S_LEN * D;
    const float* Kb  = K + (size_t)bh * S_LEN * D;
    const float* Vb  = V + (size_t)bh * S_LEN * D;
    float* outb      = out + (size_t)bh * S_LEN * D;

    const int qi0   = pass * QTILE + wave * 2;
    const int qi1   = qi0 + 1;
    const bool v0   = qi0 < nq;
    const bool v1   = qi1 < nq;
    const int qidx0 = v0 ? ql[qi0] : ql[0];
    const int qidx1 = v1 ? ql[qi1] : ql[0];

    if (nk == 0) {  // empty key bucket: reference gives all-zero rows
        if (v0) outb[(size_t)qidx0 * D + lane] = 0.0f;
        if (v1) outb[(size_t)qidx1 * D + lane] = 0.0f;
        return;
    }

    __shared__ float KtI[16][64][4];   // KtI[d4][k][j] = K[k][4*d4+j]
    __shared__ float VtI[16][64][4];   // VtI[k4][d][j] = V[4*k4+j][d]
    __shared__ float wbuf[4][2][64];

    const float* qr0 = Qb + (size_t)qidx0 * D;
    const float* qr1 = Qb + (size_t)qidx1 * D;

    float m0 = -INFINITY, l0 = 0.f, acc0 = 0.f;
    float m1 = -INFINITY, l1 = 0.f, acc1 = 0.f;

    const int nchunks = (nk + 63) >> 6;
    for (int c = 0; c < nchunks; ++c) {
        if (c > 0) __syncthreads();
        {   // stage K chunk, transposed+interleaved
            const int kk  = tid & 63;
            const int grp = tid >> 6;
            const int g   = c * 64 + kk;
            if (g < nk) {
                const float* kr = Kb + (size_t)kl[g] * D;
#pragma unroll
                for (int i = 0; i < 4; ++i) {
                    const int d4 = grp * 4 + i;
                    *(float4*)&KtI[d4][kk][0] = *(const float4*)(kr + d4 * 4);
                }
            } else {
#pragma unroll
                for (int i = 0; i < 4; ++i)
                    *(float4*)&KtI[grp * 4 + i][kk][0] = float4{0, 0, 0, 0};
            }
        }
        {   // stage V chunk
#pragma unroll
            for (int j = 0; j < 16; ++j) {
                const int r = wave * 16 + j;
                const int g = c * 64 + r;
                const float val = (g < nk) ? Vb[(size_t)kl[g] * D + lane] : 0.0f;
                VtI[r >> 2][lane][r & 3] = val;
            }
        }
        __syncthreads();

        // ---- scores: lane = key
        float s0 = 0.f, s1 = 0.f;
#pragma unroll
        for (int d4 = 0; d4 < 16; ++d4) {
            const float4 k4 = *(const float4*)&KtI[d4][lane][0];
            const float4 qa = *(const float4*)(qr0 + d4 * 4);
            const float4 qc = *(const float4*)(qr1 + d4 * 4);
            s0 += k4.x * qa.x + k4.y * qa.y + k4.z * qa.z + k4.w * qa.w;
            s1 += k4.x * qc.x + k4.y * qc.y + k4.z * qc.z + k4.w * qc.w;
        }
        s0 *= 0.125f; s1 *= 0.125f;
        const bool kvalid = (c * 64 + lane) < nk;
        if (!kvalid) { s0 = -INFINITY; s1 = -INFINITY; }

        const float cm0 = wave_max(s0), cm1 = wave_max(s1);
        const float mn0 = fmaxf(m0, cm0), mn1 = fmaxf(m1, cm1);
        const float sc0 = __expf(m0 - mn0), sc1 = __expf(m1 - mn1);
        const float e0 = kvalid ? __expf(s0 - mn0) : 0.f;
        const float e1 = kvalid ? __expf(s1 - mn1) : 0.f;
        const float cs0 = wave_sum(e0), cs1 = wave_sum(e1);
        l0 = l0 * sc0 + cs0; m0 = mn0;
        l1 = l1 * sc1 + cs1; m1 = mn1;
        acc0 *= sc0; acc1 *= sc1;

        wbuf[wave][0][lane] = e0;
        wbuf[wave][1][lane] = e1;
        // same-wave LDS RAW: compiler inserts lgkmcnt wait

        // ---- PV: lane = dim
#pragma unroll
        for (int k4 = 0; k4 < 16; ++k4) {
            const float4 v4 = *(const float4*)&VtI[k4][lane][0];
            const float4 wa = *(const float4*)&wbuf[wave][0][k4 * 4];
            const float4 wc = *(const float4*)&wbuf[wave][1][k4 * 4];
            acc0 += wa.x * v4.x + wa.y * v4.y + wa.z * v4.z + wa.w * v4.w;
            acc1 += wc.x * v4.x + wc.y * v4.y + wc.z * v4.z + wc.w * v4.w;
        }
    }

    const float inv6 = 1.0f / 6.0f;
    if (v0) outb[(size_t)qidx0 * D + lane] = acc0 / (l0 + 1e-8f) * inv6;
    if (v1) outb[(size_t)qidx1 * D + lane] = acc1 / (l1 + 1e-8f) * inv6;
}

extern "C" void kernel_launch(void* const* d_in, const int* in_sizes, int n_in,
                              void* d_out, int out_size, void* d_ws, size_t ws_size,
                              hipStream_t stream) {
    const float* Q   = (const float*)d_in[0];
    const float* K   = (const float*)d_in[1];
    const float* V   = (const float*)d_in[2];
    const float* rot = (const float*)d_in[3];
    float* out = (float*)d_out;

    char* ws = (char*)d_ws;
    int* q_buckets = (int*)(ws);              // 128 KB
    int* k_buckets = (int*)(ws + 131072);     // 128 KB
    int* q_start   = (int*)(ws + 262144);     // 8 KB (16*65*4 used)
    int* k_start   = (int*)(ws + 270336);     // 8 KB
    int* q_list    = (int*)(ws + 278528);     // 128 KB
    int* k_list    = (int*)(ws + 409600);     // 128 KB
    unsigned int* work = (unsigned int*)(ws + 540672);  // 20 KB
    int* wq_count  = (int*)(ws + 561152);     // 4 B

    lsh_buckets2<<<2 * BH * S_LEN / 4, 256, 0, stream>>>(Q, K, rot, q_buckets, k_buckets);
    lsh_build_lists2<<<32, 256, 0, stream>>>(q_buckets, k_buckets, q_start, q_list, k_start, k_list);
    build_workqueue<<<1, 1024, 0, stream>>>(q_start, work, wq_count);
    lsh_attn_wq<<<MAX_WORK, 256, 0, stream>>>(Q, K, V, q_start, q_list, k_start, k_list,
                                              work, wq_count, out);
}

// Round 4
// 131.943 us; speedup vs baseline: 1.1885x; 1.1885x over previous
//
#include <hip/hip_runtime.h>
#include <math.h>

// LSH attention: B=2, H=8, S=2048, D=64, 6 bits -> 64 buckets, exact-match.
// Phase 1: bucket codes for Q and K (fused, sign of X.rot)
// Phase 2: stable counting sort of query and key indices by bucket
// Phase 3: wave-per-query, barrier-free. lane=key for scores (per-lane K-row
//          gather vs wave-uniform Q, no per-key reduce), per-wave LDS transpose,
//          lane=dim for PV with coalesced V rows. Queries walked in bucket-
//          sorted order for L1/L2 reuse of the bucket's K/V rows.

constexpr int S_LEN = 2048;
constexpr int D = 64;
constexpr int NHASH = 6;
constexpr int BH = 16;     // B*H
constexpr int NB = 64;     // 2^NHASH

__device__ __forceinline__ float wave_sum(float v) {
#pragma unroll
    for (int off = 32; off >= 1; off >>= 1) v += __shfl_xor(v, off, 64);
    return v;
}
__device__ __forceinline__ float wave_max(float v) {
#pragma unroll
    for (int off = 32; off >= 1; off >>= 1) v = fmaxf(v, __shfl_xor(v, off, 64));
    return v;
}

// ---- Phase 1: bucket codes for Q and K in one dispatch. One wave per vector.
__global__ __launch_bounds__(256) void lsh_buckets2(const float* __restrict__ Q,
                                                    const float* __restrict__ K,
                                                    const float* __restrict__ rot,
                                                    int* __restrict__ qb,
                                                    int* __restrict__ kb) {
    const int gw   = (blockIdx.x * 256 + threadIdx.x) >> 6;
    const int lane = threadIdx.x & 63;
    const bool isK = gw >= BH * S_LEN;
    const int wid  = isK ? gw - BH * S_LEN : gw;
    const float* X = isK ? K : Q;
    int* dst       = isK ? kb : qb;
    const int h    = (wid >> 11) & 7;

    const float x  = X[(size_t)wid * D + lane];
    const float* r = rot + (size_t)h * NHASH * D + lane;
    float p0 = x * r[0 * D], p1 = x * r[1 * D], p2 = x * r[2 * D];
    float p3 = x * r[3 * D], p4 = x * r[4 * D], p5 = x * r[5 * D];
#pragma unroll
    for (int off = 32; off >= 1; off >>= 1) {
        p0 += __shfl_xor(p0, off, 64);
        p1 += __shfl_xor(p1, off, 64);
        p2 += __shfl_xor(p2, off, 64);
        p3 += __shfl_xor(p3, off, 64);
        p4 += __shfl_xor(p4, off, 64);
        p5 += __shfl_xor(p5, off, 64);
    }
    int bucket = (p0 > 0.f ? 1 : 0) | (p1 > 0.f ? 2 : 0) | (p2 > 0.f ? 4 : 0) |
                 (p3 > 0.f ? 8 : 0) | (p4 > 0.f ? 16 : 0) | (p5 > 0.f ? 32 : 0);
    if (lane == 0) dst[wid] = bucket;
}

// ---- Phase 2: stable counting sort, one block per (which, bh). which: 0=Q 1=K
__global__ __launch_bounds__(256) void lsh_build_lists2(const int* __restrict__ qbuckets,
                                                        const int* __restrict__ kbuckets,
                                                        int* __restrict__ q_start,
                                                        int* __restrict__ q_list,
                                                        int* __restrict__ k_start,
                                                        int* __restrict__ k_list) {
    __shared__ unsigned short hist[256][NB + 1];
    __shared__ int base[NB + 1];
    const int which = blockIdx.x >> 4;
    const int bh    = blockIdx.x & 15;
    const int tid   = threadIdx.x;
    const int* src  = (which ? kbuckets : qbuckets) + bh * S_LEN;
    int* bstart     = (which ? k_start : q_start) + bh * (NB + 1);
    int* blist      = (which ? k_list : q_list) + bh * S_LEN;

    for (int b = 0; b <= NB; ++b) hist[tid][b] = 0;

    int myb[8];
#pragma unroll
    for (int i = 0; i < 8; ++i) {
        int b = src[tid * 8 + i];
        myb[i] = b;
        hist[tid][b]++;
    }
    __syncthreads();

    if (tid < NB) {
        int run = 0;
        for (int c = 0; c < 256; ++c) {
            int t = hist[c][tid];
            hist[c][tid] = (unsigned short)run;
            run += t;
        }
        base[tid] = run;
    }
    __syncthreads();

    if (tid == 0) {
        int run = 0;
        for (int b = 0; b < NB; ++b) {
            int t = base[b];
            base[b] = run;
            bstart[b] = run;
            run += t;
        }
        base[NB] = run;
        bstart[NB] = run;
    }
    __syncthreads();

#pragma unroll
    for (int i = 0; i < 8; ++i) {
        int b   = myb[i];
        int ofs = base[b] + hist[tid][b];
        hist[tid][b]++;
        blist[ofs] = tid * 8 + i;
    }
}

// ---- Phase 3: wave per query, no block barriers.
__global__ __launch_bounds__(256) void lsh_attn_gather(const float* __restrict__ Q,
                                                       const float* __restrict__ K,
                                                       const float* __restrict__ V,
                                                       const int* __restrict__ q_buckets,
                                                       const int* __restrict__ q_list,
                                                       const int* __restrict__ k_start,
                                                       const int* __restrict__ k_list,
                                                       float* __restrict__ out) {
    __shared__ float wbuf[4][64];   // per-wave e transpose buffer
    __shared__ int   kbuf[4][64];   // per-wave key-index transpose buffer

    const int gw   = (blockIdx.x * 256 + threadIdx.x) >> 6;  // [0, BH*S)
    const int wv   = (threadIdx.x >> 6);
    const int lane = threadIdx.x & 63;
    const int bh   = gw >> 11;
    const int i    = gw & (S_LEN - 1);

    const int qidx   = q_list[bh * S_LEN + i];                // wave-uniform
    const int bucket = q_buckets[bh * S_LEN + qidx];          // wave-uniform
    const int ks = k_start[bh * (NB + 1) + bucket];
    const int ke = k_start[bh * (NB + 1) + bucket + 1];
    const int nk = ke - ks;

    float* orow = out + ((size_t)bh * S_LEN + qidx) * D;
    if (nk == 0) { orow[lane] = 0.0f; return; }

    const int* kl     = k_list + bh * S_LEN + ks;
    const float* qrow = Q + ((size_t)bh * S_LEN + qidx) * D;
    const float* Kb   = K + (size_t)bh * S_LEN * D;
    const float* Vb   = V + (size_t)bh * S_LEN * D;

    float m = -INFINITY, l = 0.0f, acc = 0.0f;

    for (int c = 0; c * 64 < nk; ++c) {
        const int cnk  = min(64, nk - c * 64);
        const int kidx = kl[c * 64 + min(lane, cnk - 1)];     // coalesced, clamped

        // ---- scores: lane = key; per-lane K-row gather vs uniform Q
        const float* krow = Kb + (size_t)kidx * D;
        float s = 0.0f;
#pragma unroll
        for (int d4 = 0; d4 < 16; ++d4) {
            const float4 qv = *(const float4*)(qrow + d4 * 4);   // wave-uniform
            const float4 kv = *(const float4*)(krow + d4 * 4);   // gather
            s += qv.x * kv.x + qv.y * kv.y + qv.z * kv.z + qv.w * kv.w;
        }
        s *= 0.125f;
        const bool kvalid = lane < cnk;
        if (!kvalid) s = -INFINITY;

        const float cm = wave_max(s);
        const float mn = fmaxf(m, cm);
        const float sc = __expf(m - mn);                      // exp(-inf)=0 first time
        const float e  = kvalid ? __expf(s - mn) : 0.0f;
        l   = l * sc + wave_sum(e);
        acc = acc * sc;
        m   = mn;

        wbuf[wv][lane] = e;
        kbuf[wv][lane] = kidx;
        // same-wave LDS RAW: compiler inserts lgkmcnt wait

        // ---- PV: lane = dim; coalesced V rows, weights broadcast from LDS
        const int ng = (cnk + 3) >> 2;
        for (int g = 0; g < ng; ++g) {
            const float4 ee = *(const float4*)&wbuf[wv][g * 4];  // uniform broadcast
            const int4   kk = *(const int4*)&kbuf[wv][g * 4];
            acc += ee.x * Vb[(size_t)kk.x * D + lane];
            acc += ee.y * Vb[(size_t)kk.y * D + lane];
            acc += ee.z * Vb[(size_t)kk.z * D + lane];
            acc += ee.w * Vb[(size_t)kk.w * D + lane];
        }
    }

    orow[lane] = acc / (l + 1e-8f) * (1.0f / 6.0f);
}

extern "C" void kernel_launch(void* const* d_in, const int* in_sizes, int n_in,
                              void* d_out, int out_size, void* d_ws, size_t ws_size,
                              hipStream_t stream) {
    const float* Q   = (const float*)d_in[0];
    const float* K   = (const float*)d_in[1];
    const float* V   = (const float*)d_in[2];
    const float* rot = (const float*)d_in[3];
    float* out = (float*)d_out;

    char* ws = (char*)d_ws;
    int* q_buckets = (int*)(ws);              // 128 KB
    int* k_buckets = (int*)(ws + 131072);     // 128 KB
    int* q_start   = (int*)(ws + 262144);     // 8 KB (16*65*4 used)
    int* k_start   = (int*)(ws + 270336);     // 8 KB
    int* q_list    = (int*)(ws + 278528);     // 128 KB
    int* k_list    = (int*)(ws + 409600);     // 128 KB

    lsh_buckets2<<<2 * BH * S_LEN / 4, 256, 0, stream>>>(Q, K, rot, q_buckets, k_buckets);
    lsh_build_lists2<<<32, 256, 0, stream>>>(q_buckets, k_buckets, q_start, q_list, k_start, k_list);
    lsh_attn_gather<<<BH * S_LEN / 4, 256, 0, stream>>>(Q, K, V, q_buckets, q_list,
                                                        k_start, k_list, out);
}

// Round 5
// 78.314 us; speedup vs baseline: 2.0024x; 1.6848x over previous
//
#include <hip/hip_runtime.h>
#include <math.h>

// LSH attention: B=2, H=8, S=2048, D=64, 6 bits -> 64 buckets, exact-match.
// Phase 1: bucket codes for Q and K (fused, sign of X.rot)
// Phase 2: stable counting sort; Q list is 4-PADDED per bucket (sentinel -1)
//          so each aligned 4-group of sorted queries is same-bucket.
// Phase 3: wave per 4 queries (same bucket), barrier-free. lane=key scores:
//          per-lane K-row gather shared by 4 queries; scalar (s_load) Q reads;
//          per-wave LDS transpose; lane=dim PV with V rows shared by 4 queries.

constexpr int S_LEN = 2048;
constexpr int D = 64;
constexpr int NHASH = 6;
constexpr int BH = 16;     // B*H
constexpr int NB = 64;     // 2^NHASH
constexpr int PADQ = S_LEN + 3 * NB;   // 2240: worst-case 4-padded length per bh

__device__ __forceinline__ float wave_sum(float v) {
#pragma unroll
    for (int off = 32; off >= 1; off >>= 1) v += __shfl_xor(v, off, 64);
    return v;
}

// ---- Phase 1: bucket codes for Q and K in one dispatch. One wave per vector.
__global__ __launch_bounds__(256) void lsh_buckets2(const float* __restrict__ Q,
                                                    const float* __restrict__ K,
                                                    const float* __restrict__ rot,
                                                    int* __restrict__ qb,
                                                    int* __restrict__ kb) {
    const int gw   = (blockIdx.x * 256 + threadIdx.x) >> 6;
    const int lane = threadIdx.x & 63;
    const bool isK = gw >= BH * S_LEN;
    const int wid  = isK ? gw - BH * S_LEN : gw;
    const float* X = isK ? K : Q;
    int* dst       = isK ? kb : qb;
    const int h    = (wid >> 11) & 7;

    const float x  = X[(size_t)wid * D + lane];
    const float* r = rot + (size_t)h * NHASH * D + lane;
    float p0 = x * r[0 * D], p1 = x * r[1 * D], p2 = x * r[2 * D];
    float p3 = x * r[3 * D], p4 = x * r[4 * D], p5 = x * r[5 * D];
#pragma unroll
    for (int off = 32; off >= 1; off >>= 1) {
        p0 += __shfl_xor(p0, off, 64);
        p1 += __shfl_xor(p1, off, 64);
        p2 += __shfl_xor(p2, off, 64);
        p3 += __shfl_xor(p3, off, 64);
        p4 += __shfl_xor(p4, off, 64);
        p5 += __shfl_xor(p5, off, 64);
    }
    int bucket = (p0 > 0.f ? 1 : 0) | (p1 > 0.f ? 2 : 0) | (p2 > 0.f ? 4 : 0) |
                 (p3 > 0.f ? 8 : 0) | (p4 > 0.f ? 16 : 0) | (p5 > 0.f ? 32 : 0);
    if (lane == 0) dst[wid] = bucket;
}

// ---- Phase 2: stable counting sort, one block per (which, bh). which: 0=Q 1=K
// Q side writes a 4-padded list (PADQ slots, -1 sentinels); K side unpadded +
// bucket_start table.
__global__ __launch_bounds__(256) void lsh_build_lists3(const int* __restrict__ qbuckets,
                                                        const int* __restrict__ kbuckets,
                                                        int* __restrict__ q_plist,
                                                        int* __restrict__ k_start,
                                                        int* __restrict__ k_list) {
    __shared__ unsigned short hist[256][NB + 1];
    __shared__ int base[NB + 1];
    const int which = blockIdx.x >> 4;   // 0 = Q (padded), 1 = K
    const int bh    = blockIdx.x & 15;
    const int tid   = threadIdx.x;
    const int* src  = (which ? kbuckets : qbuckets) + bh * S_LEN;
    int* blist      = which ? (k_list + bh * S_LEN) : (q_plist + bh * PADQ);

    if (!which) {  // prefill padded list with sentinels
        for (int t = tid; t < PADQ; t += 256) blist[t] = -1;
    }

    for (int b = 0; b <= NB; ++b) hist[tid][b] = 0;

    int myb[8];
#pragma unroll
    for (int i = 0; i < 8; ++i) {
        int b = src[tid * 8 + i];
        myb[i] = b;
        hist[tid][b]++;
    }
    __syncthreads();

    // per-bucket exclusive prefix over chunks -> hist becomes WITHIN-BUCKET offset
    if (tid < NB) {
        int run = 0;
        for (int c = 0; c < 256; ++c) {
            int t = hist[c][tid];
            hist[c][tid] = (unsigned short)run;
            run += t;
        }
        base[tid] = run;   // bucket count
    }
    __syncthreads();

    if (tid == 0) {
        int run = 0;
        if (which) {
            int* bstart = k_start + bh * (NB + 1);
            for (int b = 0; b < NB; ++b) {
                int t = base[b];
                base[b] = run;
                bstart[b] = run;
                run += t;
            }
            base[NB] = run;
            bstart[NB] = run;
        } else {
            for (int b = 0; b < NB; ++b) {
                int t = base[b];
                base[b] = run;                 // padded start
                run += (t + 3) & ~3;           // pad to multiple of 4
            }
        }
    }
    __syncthreads();

    // stable placement: slot = bucket_start + within-bucket offset
#pragma unroll
    for (int i = 0; i < 8; ++i) {
        int b   = myb[i];
        int ofs = base[b] + hist[tid][b];
        hist[tid][b]++;
        blist[ofs] = tid * 8 + i;
    }
}

// ---- Phase 3: wave per 4 same-bucket queries, no block barriers.
__global__ __launch_bounds__(256) void lsh_attn_g4(const float* __restrict__ Q,
                                                   const float* __restrict__ K,
                                                   const float* __restrict__ V,
                                                   const int* __restrict__ q_buckets,
                                                   const int* __restrict__ q_plist,
                                                   const int* __restrict__ k_start,
                                                   const int* __restrict__ k_list,
                                                   float* __restrict__ out) {
    __shared__ float wbuf[4][4][64];   // [wave][query][key-lane]
    __shared__ int   kbuf[4][64];

    const int wv   = threadIdx.x >> 6;
    const int lane = threadIdx.x & 63;
    const int bh   = blockIdx.y;
    const int slot = (blockIdx.x * 4 + wv) * 4;        // [0, 2240)

    const int* pl = q_plist + bh * PADQ + slot;
    const int q0 = __builtin_amdgcn_readfirstlane(pl[0]);
    if (q0 < 0) return;                                 // all-sentinel group
    int q1 = __builtin_amdgcn_readfirstlane(pl[1]);
    int q2 = __builtin_amdgcn_readfirstlane(pl[2]);
    int q3 = __builtin_amdgcn_readfirstlane(pl[3]);
    const bool v1 = q1 >= 0, v2 = q2 >= 0, v3 = q3 >= 0;
    if (!v1) q1 = q0;
    if (!v2) q2 = q0;
    if (!v3) q3 = q0;

    const int bucket = __builtin_amdgcn_readfirstlane(q_buckets[bh * S_LEN + q0]);
    const int ks = k_start[bh * (NB + 1) + bucket];
    const int ke = k_start[bh * (NB + 1) + bucket + 1];
    const int nk = ke - ks;

    float* outb = out + (size_t)bh * S_LEN * D;
    if (nk == 0) {   // empty key bucket -> zero rows
        outb[(size_t)q0 * D + lane] = 0.0f;
        if (v1) outb[(size_t)q1 * D + lane] = 0.0f;
        if (v2) outb[(size_t)q2 * D + lane] = 0.0f;
        if (v3) outb[(size_t)q3 * D + lane] = 0.0f;
        return;
    }

    const int* kl     = k_list + bh * S_LEN + ks;
    const float* Kb   = K + (size_t)bh * S_LEN * D;
    const float* Vb   = V + (size_t)bh * S_LEN * D;
    const float* qr0  = Q + ((size_t)bh * S_LEN + q0) * D;   // scalar-base (s_load)
    const float* qr1  = Q + ((size_t)bh * S_LEN + q1) * D;
    const float* qr2  = Q + ((size_t)bh * S_LEN + q2) * D;
    const float* qr3  = Q + ((size_t)bh * S_LEN + q3) * D;

    float m0 = -INFINITY, l0 = 0.f, acc0 = 0.f;
    float m1 = -INFINITY, l1 = 0.f, acc1 = 0.f;
    float m2 = -INFINITY, l2 = 0.f, acc2 = 0.f;
    float m3 = -INFINITY, l3 = 0.f, acc3 = 0.f;

    for (int c = 0; c * 64 < nk; ++c) {
        const int cnk  = min(64, nk - c * 64);
        const int kidx = kl[c * 64 + min(lane, cnk - 1)];   // coalesced, clamped
        const float* krow = Kb + (size_t)kidx * D;

        // ---- scores: lane = key; K-row gather shared by 4 queries
        float s0 = 0.f, s1 = 0.f, s2 = 0.f, s3 = 0.f;
#pragma unroll
        for (int d4 = 0; d4 < 16; ++d4) {
            const float4 kv = *(const float4*)(krow + d4 * 4);   // gather
            const float4 a  = *(const float4*)(qr0 + d4 * 4);    // scalar loads
            const float4 b  = *(const float4*)(qr1 + d4 * 4);
            const float4 cq = *(const float4*)(qr2 + d4 * 4);
            const float4 dq = *(const float4*)(qr3 + d4 * 4);
            s0 += a.x * kv.x + a.y * kv.y + a.z * kv.z + a.w * kv.w;
            s1 += b.x * kv.x + b.y * kv.y + b.z * kv.z + b.w * kv.w;
            s2 += cq.x * kv.x + cq.y * kv.y + cq.z * kv.z + cq.w * kv.w;
            s3 += dq.x * kv.x + dq.y * kv.y + dq.z * kv.z + dq.w * kv.w;
        }
        const bool kvalid = lane < cnk;
        const float NEG = -INFINITY;
        s0 = kvalid ? s0 * 0.125f : NEG;
        s1 = kvalid ? s1 * 0.125f : NEG;
        s2 = kvalid ? s2 * 0.125f : NEG;
        s3 = kvalid ? s3 * 0.125f : NEG;

        // interleaved wave max (4 trees)
        float c0 = s0, c1 = s1, c2 = s2, c3 = s3;
#pragma unroll
        for (int off = 32; off >= 1; off >>= 1) {
            c0 = fmaxf(c0, __shfl_xor(c0, off, 64));
            c1 = fmaxf(c1, __shfl_xor(c1, off, 64));
            c2 = fmaxf(c2, __shfl_xor(c2, off, 64));
            c3 = fmaxf(c3, __shfl_xor(c3, off, 64));
        }
        const float mn0 = fmaxf(m0, c0), mn1 = fmaxf(m1, c1);
        const float mn2 = fmaxf(m2, c2), mn3 = fmaxf(m3, c3);
        const float sc0 = __expf(m0 - mn0), sc1 = __expf(m1 - mn1);
        const float sc2 = __expf(m2 - mn2), sc3 = __expf(m3 - mn3);
        const float e0 = kvalid ? __expf(s0 - mn0) : 0.f;
        const float e1 = kvalid ? __expf(s1 - mn1) : 0.f;
        const float e2 = kvalid ? __expf(s2 - mn2) : 0.f;
        const float e3 = kvalid ? __expf(s3 - mn3) : 0.f;
        // interleaved wave sum (4 trees)
        float t0 = e0, t1 = e1, t2 = e2, t3 = e3;
#pragma unroll
        for (int off = 32; off >= 1; off >>= 1) {
            t0 += __shfl_xor(t0, off, 64);
            t1 += __shfl_xor(t1, off, 64);
            t2 += __shfl_xor(t2, off, 64);
            t3 += __shfl_xor(t3, off, 64);
        }
        l0 = l0 * sc0 + t0; m0 = mn0; acc0 *= sc0;
        l1 = l1 * sc1 + t1; m1 = mn1; acc1 *= sc1;
        l2 = l2 * sc2 + t2; m2 = mn2; acc2 *= sc2;
        l3 = l3 * sc3 + t3; m3 = mn3; acc3 *= sc3;

        wbuf[wv][0][lane] = e0;
        wbuf[wv][1][lane] = e1;
        wbuf[wv][2][lane] = e2;
        wbuf[wv][3][lane] = e3;
        kbuf[wv][lane]    = kidx;
        // same-wave LDS RAW: compiler inserts lgkmcnt wait

        // ---- PV: lane = dim; V rows shared by 4 queries
        const int ng = (cnk + 3) >> 2;
        for (int g = 0; g < ng; ++g) {
            const int4   kk = *(const int4*)&kbuf[wv][g * 4];
            const float4 ea = *(const float4*)&wbuf[wv][0][g * 4];
            const float4 eb = *(const float4*)&wbuf[wv][1][g * 4];
            const float4 ec = *(const float4*)&wbuf[wv][2][g * 4];
            const float4 ed = *(const float4*)&wbuf[wv][3][g * 4];
            const float vx = Vb[(size_t)kk.x * D + lane];
            const float vy = Vb[(size_t)kk.y * D + lane];
            const float vz = Vb[(size_t)kk.z * D + lane];
            const float vw = Vb[(size_t)kk.w * D + lane];
            acc0 += ea.x * vx + ea.y * vy + ea.z * vz + ea.w * vw;
            acc1 += eb.x * vx + eb.y * vy + eb.z * vz + eb.w * vw;
            acc2 += ec.x * vx + ec.y * vy + ec.z * vz + ec.w * vw;
            acc3 += ed.x * vx + ed.y * vy + ed.z * vz + ed.w * vw;
        }
    }

    const float inv6 = 1.0f / 6.0f;
    outb[(size_t)q0 * D + lane] = acc0 / (l0 + 1e-8f) * inv6;
    if (v1) outb[(size_t)q1 * D + lane] = acc1 / (l1 + 1e-8f) * inv6;
    if (v2) outb[(size_t)q2 * D + lane] = acc2 / (l2 + 1e-8f) * inv6;
    if (v3) outb[(size_t)q3 * D + lane] = acc3 / (l3 + 1e-8f) * inv6;
}

extern "C" void kernel_launch(void* const* d_in, const int* in_sizes, int n_in,
                              void* d_out, int out_size, void* d_ws, size_t ws_size,
                              hipStream_t stream) {
    const float* Q   = (const float*)d_in[0];
    const float* K   = (const float*)d_in[1];
    const float* V   = (const float*)d_in[2];
    const float* rot = (const float*)d_in[3];
    float* out = (float*)d_out;

    char* ws = (char*)d_ws;
    int* q_buckets = (int*)(ws);              // 128 KB
    int* k_buckets = (int*)(ws + 131072);     // 128 KB
    int* k_start   = (int*)(ws + 262144);     // 8 KB (16*65*4 used)
    int* k_list    = (int*)(ws + 270336);     // 128 KB
    int* q_plist   = (int*)(ws + 401408);     // 16*2240*4 = 140 KB

    lsh_buckets2<<<2 * BH * S_LEN / 4, 256, 0, stream>>>(Q, K, rot, q_buckets, k_buckets);
    lsh_build_lists3<<<32, 256, 0, stream>>>(q_buckets, k_buckets, q_plist, k_start, k_list);
    lsh_attn_g4<<<dim3(PADQ / 16, BH), 256, 0, stream>>>(Q, K, V, q_buckets, q_plist,
                                                         k_start, k_list, out);
}